// Round 7
// baseline (314.921 us; speedup 1.0000x reference)
//
#include <hip/hip_runtime.h>

// Problem: VoxelMorph flow pipeline.
// features [16,128,128,128] f32, moving_label [1,128,128,128] f32,
// weight [3,16,3,3,3] f32, bias [3] f32.
// Output: moved [128^3] then flow [3*128^3], f32, concatenated flat.
//
// R11: 3 dispatches (was 5). R6 showed ds_kernel+f23 == in-f2 downsample
// exactly (rest-of-pipeline constant at ~199us while work moved around) ->
// phase cost is dominated by dispatch boundaries (~25us each), not kernels.
// Halo-recompute lets adjacent steps fuse without grid sync:
//   conv : unchanged from R6 (93.4us, VALUBusy 51%, conflicts 131K)
//   f2b  : downsample(1/256) on 14^3 halo + steps 1-3 -> g3 (64^3)
//   f47  : stage g3 on 19^3 halo, steps 4-7 (19->17->15->13->11 ping-pong),
//          then upsample(x2) + label warp. LDS 141.3KB, 1 block/CU.
// Intermediates interleaved [vox][3] (12B/corner gathers).

#define V128 2097152      // 128^3
#define V64  262144       // 64^3

typedef __attribute__((ext_vector_type(2))) float f32x2;
typedef float f32x2u __attribute__((ext_vector_type(2), aligned(4)));

// ---------------- trilinear sampler (bounds-checked; label warp) -----------
template <int C>
__device__ __forceinline__ void trisample(const float* __restrict__ vol,
                                          int D, int H, int W, int cstride,
                                          float cz, float cy, float cx,
                                          float* out) {
    float fz = floorf(cz), fy = floorf(cy), fx = floorf(cx);
    int iz = (int)fz, iy = (int)fy, ix = (int)fx;
    float tz = cz - fz, ty = cy - fy, tx = cx - fx;
#pragma unroll
    for (int c = 0; c < C; ++c) out[c] = 0.0f;
#pragma unroll
    for (int dz = 0; dz < 2; ++dz) {
#pragma unroll
        for (int dy = 0; dy < 2; ++dy) {
#pragma unroll
            for (int dx = 0; dx < 2; ++dx) {
                int z = iz + dz, y = iy + dy, x = ix + dx;
                float w = (dz ? tz : 1.0f - tz) *
                          (dy ? ty : 1.0f - ty) *
                          (dx ? tx : 1.0f - tx);
                bool valid = (z >= 0) && (z < D) && (y >= 0) && (y < H) &&
                             (x >= 0) && (x < W);
                int zc = min(max(z, 0), D - 1);
                int yc = min(max(y, 0), H - 1);
                int xc = min(max(x, 0), W - 1);
                int base = (zc * H + yc) * W + xc;
                float wv = valid ? w : 0.0f;
#pragma unroll
                for (int c = 0; c < C; ++c)
                    out[c] += vol[c * cstride + base] * wv;
            }
        }
    }
}

// -------- LDS trilerp, 3 channels, no bounds checks (caller guarantees) ----
template <int SI>
__device__ __forceinline__ void lds_lerp3(const float* __restrict__ f,
                                          float pz, float py, float px,
                                          float* out) {
    constexpr int NI = SI * SI * SI;
    float fz = floorf(pz), fy = floorf(py), fx = floorf(px);
    int iz = (int)fz, iy = (int)fy, ix = (int)fx;
    float tz = pz - fz, ty = py - fy, tx = px - fx;
    int b = (iz * SI + iy) * SI + ix;
    float wz0 = 1.0f - tz, wy0 = 1.0f - ty, wx0 = 1.0f - tx;
#pragma unroll
    for (int c = 0; c < 3; ++c) {
        const float* fc = f + c * NI;
        float v00 = fc[b] * wx0 + fc[b + 1] * tx;
        float v01 = fc[b + SI] * wx0 + fc[b + SI + 1] * tx;
        float v10 = fc[b + SI * SI] * wx0 + fc[b + SI * SI + 1] * tx;
        float v11 = fc[b + SI * SI + SI] * wx0 + fc[b + SI * SI + SI + 1] * tx;
        out[c] = wz0 * (wy0 * v00 + ty * v01) + tz * (wy0 * v10 + ty * v11);
    }
}

// -------- one integration step LDS->LDS; NT = threads in block -------------
// out region = in region shrunk by 1 per side; out frame base = in base + 1.
template <int SI, int NT>
__device__ __forceinline__ void step_lds(const float* __restrict__ in,
                                         float* __restrict__ out, int tid) {
    constexpr int SO = SI - 2;
    constexpr int NI = SI * SI * SI;
    constexpr int NO = SO * SO * SO;
    for (int i = tid; i < NO; i += NT) {
        int xx = i % SO, yy = (i / SO) % SO, zz = i / (SO * SO);
        int la = ((zz + 1) * SI + (yy + 1)) * SI + (xx + 1);
        float fz = in[la], fy = in[la + NI], fx = in[la + 2 * NI];
        float sm[3];
        lds_lerp3<SI>(in, (zz + 1) + fz, (yy + 1) + fy, (xx + 1) + fx, sm);
        out[i] = fz + sm[0];
        out[i + NO] = fy + sm[1];
        out[i + 2 * NO] = fx + sm[2];
    }
}

// -------- last f2b step: 10^3 region -> global 8^3, interleaved [vox][3] ---
template <int NT>
__device__ __forceinline__ void step_to_global(const float* __restrict__ in,
                                               float* __restrict__ gout,
                                               int tx, int ty, int tz,
                                               int tid) {
    constexpr int SI = 10;
    constexpr int NI = SI * SI * SI;
    for (int i = tid; i < 512; i += NT) {
        int xx = i & 7, yy = (i >> 3) & 7, zz = i >> 6;
        int la = ((zz + 1) * SI + (yy + 1)) * SI + (xx + 1);
        float fz = in[la], fy = in[la + NI], fx = in[la + 2 * NI];
        float sm[3];
        lds_lerp3<SI>(in, (zz + 1) + fz, (yy + 1) + fy, (xx + 1) + fx, sm);
        int n3 = ((((tz + zz) << 12) + ((ty + yy) << 6) + (tx + xx))) * 3;
        gout[n3] = fz + sm[0];
        gout[n3 + 1] = fy + sm[1];
        gout[n3 + 2] = fx + sm[2];
    }
}

// ---------------- K1: conv3d 16->3, 3x3x3, pad 1 (unchanged from R10) ------
// Global staging x-innermost (coalesced 66-float runs); LDS z-innermost
// stride-11 (bank 11*lane mod 32 bijective -> conflict-free); packed f32x2
// z-pair accumulation (v_pk_fma_f32). Output interleaved [vox][3].
__global__ __launch_bounds__(256) void conv_kernel(
    const float* __restrict__ feat, const float* __restrict__ weight,
    const float* __restrict__ bias, float* __restrict__ pf) {
    __shared__ float smem[2][4356];  // 396 columns * 11
    const int tid = threadIdx.x;
    const int x0 = blockIdx.x * 64, y0 = blockIdx.y * 4, z0 = blockIdx.z * 8;
    const int lx = tid & 63, ly = tid >> 6;

    int goff[16];
    int laddr[16];
    unsigned vmask = 0;
#pragma unroll
    for (int k = 0; k < 16; ++k) {
        int s = tid + 256 * k;
        int xx = s % 66;
        int r = s / 66;
        int yy = r % 6;
        int zz = r / 6;
        laddr[k] = (yy * 66 + xx) * 11 + zz;
        bool intile = (k < 15) || (tid < 120);
        int gx = x0 + xx - 1, gy = y0 + yy - 1, gz = z0 + zz - 1;
        bool ok = intile && ((unsigned)gx < 128u) && ((unsigned)gy < 128u) &&
                  ((unsigned)gz < 128u);
        goff[k] = (gz << 14) + (gy << 7) + gx;
        if (ok) vmask |= (1u << k);
    }

    f32x2 acc[3][4];
#pragma unroll
    for (int o = 0; o < 3; ++o)
#pragma unroll
        for (int zp = 0; zp < 4; ++zp) acc[o][zp] = (f32x2)(0.0f);

    {
        float vals[16];
#pragma unroll
        for (int k = 0; k < 16; ++k) {
            vals[k] = 0.0f;
            if (vmask & (1u << k)) vals[k] = feat[goff[k]];
        }
#pragma unroll
        for (int k = 0; k < 16; ++k)
            if (k < 15 || tid < 120) smem[0][laddr[k]] = vals[k];
    }

    for (int c = 0; c < 16; ++c) {
        __syncthreads();
        if (c + 1 < 16) {
            const float* fc = feat + ((c + 1) << 21);
            float* buf = smem[(c + 1) & 1];
            float vals[16];
#pragma unroll
            for (int k = 0; k < 16; ++k) {
                vals[k] = 0.0f;
                if (vmask & (1u << k)) vals[k] = fc[goff[k]];
            }
#pragma unroll
            for (int k = 0; k < 16; ++k)
                if (k < 15 || tid < 120) buf[laddr[k]] = vals[k];
        }
        const float* buf = smem[c & 1];
        const float* wc = weight + c * 27;
#pragma unroll
        for (int dy = 0; dy < 3; ++dy) {
#pragma unroll
            for (int dx = 0; dx < 3; ++dx) {
                const float* p = buf + ((ly + dy) * 66 + lx + dx) * 11;
                f32x2 pv[5];
                f32x2 qv[4];
#pragma unroll
                for (int k2 = 0; k2 < 5; ++k2)
                    pv[k2] = *(const f32x2u*)(p + 2 * k2);
#pragma unroll
                for (int k2 = 0; k2 < 4; ++k2)
                    qv[k2] = *(const f32x2u*)(p + 2 * k2 + 1);
#pragma unroll
                for (int o = 0; o < 3; ++o) {
                    float w0 = wc[o * 432 + 0 + dy * 3 + dx];
                    float w1 = wc[o * 432 + 9 + dy * 3 + dx];
                    float w2 = wc[o * 432 + 18 + dy * 3 + dx];
#pragma unroll
                    for (int zp = 0; zp < 4; ++zp) {
                        acc[o][zp] += pv[zp] * (f32x2)(w0);
                        acc[o][zp] += qv[zp] * (f32x2)(w1);
                        acc[o][zp] += pv[zp + 1] * (f32x2)(w2);
                    }
                }
            }
        }
    }

    float b0 = bias[0], b1 = bias[1], b2 = bias[2];
#pragma unroll
    for (int zp = 0; zp < 4; ++zp) {
        int vox0 = ((z0 + 2 * zp) << 14) + ((y0 + ly) << 7) + x0 + lx;
#pragma unroll
        for (int h = 0; h < 2; ++h) {
            int m3 = (vox0 + (h << 14)) * 3;
            pf[m3] = (h ? acc[0][zp].y : acc[0][zp].x) + b0;
            pf[m3 + 1] = (h ? acc[1][zp].y : acc[1][zp].x) + b1;
            pf[m3 + 2] = (h ? acc[2][zp].y : acc[2][zp].x) + b2;
        }
    }
}

// ------- K2 (f2b): downsample(1/256) on 14^3 halo + steps 1-3 -> g3 --------
// pf interleaved [vox][3]; each corner one 12B load. Corner base clamped to
// <=126/dim (coord exactly 127.0 -> i=126,t=1.0 == zero-weight corner).
__global__ __launch_bounds__(512) void f2b_kernel(
    const float* __restrict__ pf, float* __restrict__ gout) {
    __shared__ float A[3 * 2744];  // 14^3
    __shared__ float B[3 * 1728];  // 12^3
    const int tid = threadIdx.x;
    const int tx = blockIdx.x * 8, ty = blockIdx.y * 8, tz = blockIdx.z * 8;
    const int rbx = tx - 3, rby = ty - 3, rbz = tz - 3;
    const float s2 = 127.0f / 63.0f;
    const float k = 1.0f / 256.0f;
    for (int i = tid; i < 2744; i += 512) {
        int xx = i % 14, yy = (i / 14) % 14, zz = i / 196;
        int gz = rbz + zz, gy = rby + yy, gx = rbx + xx;
        float v0 = 0.0f, v1 = 0.0f, v2 = 0.0f;
        if ((unsigned)gz < 64u && (unsigned)gy < 64u && (unsigned)gx < 64u) {
            float cz = gz * s2, cy = gy * s2, cx = gx * s2;
            int iz = min((int)cz, 126);
            int iy = min((int)cy, 126);
            int ix = min((int)cx, 126);
            float tzf = cz - (float)iz;
            float tyf = cy - (float)iy;
            float txf = cx - (float)ix;
            float wz[2] = {1.0f - tzf, tzf};
            float wy[2] = {1.0f - tyf, tyf};
            float wx[2] = {1.0f - txf, txf};
            int b = ((iz << 14) + (iy << 7) + ix) * 3;
#pragma unroll
            for (int dz = 0; dz < 2; ++dz)
#pragma unroll
                for (int dy = 0; dy < 2; ++dy)
#pragma unroll
                    for (int dx = 0; dx < 2; ++dx) {
                        float w = wz[dz] * wy[dy] * wx[dx];
                        int bb = b + dz * (3 << 14) + dy * (3 << 7) + dx * 3;
                        v0 += pf[bb] * w;
                        v1 += pf[bb + 1] * w;
                        v2 += pf[bb + 2] * w;
                    }
        }
        A[i] = v0 * k;
        A[i + 2744] = v1 * k;
        A[i + 2 * 2744] = v2 * k;
    }
    __syncthreads();
    step_lds<14, 512>(A, B, tid);  // s1: 12^3 in B
    __syncthreads();
    step_lds<12, 512>(B, A, tid);  // s2: 10^3 into A-mem
    __syncthreads();
    step_to_global<512>(A, gout, tx, ty, tz, tid);  // s3 -> 8^3 global
}

// ------- K3 (f47): steps 4-7 + upsample(x2) + label warp -------------------
// Per 16^3 output tile: upsample reads g7 on [r0, r0+10]; chain needs g3 on
// [r0-4, r0+14] (19^3). Ping-pong: A19 -> B17 -> A15 -> B13 -> A11.
// LDS = 3*(19^3 + 17^3)*4 = 141,264 B -> 1 block/CU.
__global__ __launch_bounds__(512) void f47_kernel(
    const float* __restrict__ gin, const float* __restrict__ label,
    float* __restrict__ moved, float* __restrict__ flow) {
    __shared__ float A[3 * 6859];  // 19^3 (also holds 15^3, 11^3)
    __shared__ float B[3 * 4913];  // 17^3 (also holds 13^3)
    const int tid = threadIdx.x;
    const int ttx = blockIdx.x, tty = blockIdx.y, ttz = blockIdx.z;
    const int r0x = (1008 * ttx) / 127 - 1;
    const int r0y = (1008 * tty) / 127 - 1;
    const int r0z = (1008 * ttz) / 127 - 1;
    const int rbx = r0x - 4, rby = r0y - 4, rbz = r0z - 4;
    // stage g3 on 19^3, zero-extended outside [0,64)^3
    for (int i = tid; i < 6859; i += 512) {
        int xx = i % 19, yy = (i / 19) % 19, zz = i / 361;
        int gz = rbz + zz, gy = rby + yy, gx = rbx + xx;
        float v0 = 0.0f, v1 = 0.0f, v2 = 0.0f;
        if ((unsigned)gz < 64u && (unsigned)gy < 64u && (unsigned)gx < 64u) {
            int n3 = ((gz << 12) + (gy << 6) + gx) * 3;
            v0 = gin[n3];
            v1 = gin[n3 + 1];
            v2 = gin[n3 + 2];
        }
        A[i] = v0;
        A[i + 6859] = v1;
        A[i + 2 * 6859] = v2;
    }
    __syncthreads();
    step_lds<19, 512>(A, B, tid);  // s4: g4 17^3, frame rb+1
    __syncthreads();
    step_lds<17, 512>(B, A, tid);  // s5: g5 15^3, frame rb+2
    __syncthreads();
    step_lds<15, 512>(A, B, tid);  // s6: g6 13^3, frame rb+3
    __syncthreads();
    step_lds<13, 512>(B, A, tid);  // s7: g7 11^3, frame rb+4 = r0
    __syncthreads();
    const float s3 = 63.0f / 127.0f;
    for (int i = tid; i < 4096; i += 512) {
        int lx = i & 15, ly = (i >> 4) & 15, lz = i >> 8;
        int gx = ttx * 16 + lx, gy = tty * 16 + ly, gz = ttz * 16 + lz;
        float f[3];
        lds_lerp3<11>(A, gz * s3 - (float)r0z, gy * s3 - (float)r0y,
                      gx * s3 - (float)r0x, f);
        float fz = 2.0f * f[0], fy = 2.0f * f[1], fx = 2.0f * f[2];
        int m = (gz << 14) + (gy << 7) + gx;
        flow[m] = fz;
        flow[m + V128] = fy;
        flow[m + 2 * V128] = fx;
        float mv[1];
        trisample<1>(label, 128, 128, 128, 0, gz + fz, gy + fy, gx + fx, mv);
        moved[m] = mv[0];
    }
}

extern "C" void kernel_launch(void* const* d_in, const int* in_sizes, int n_in,
                              void* d_out, int out_size, void* d_ws,
                              size_t ws_size, hipStream_t stream) {
    const float* features = (const float*)d_in[0];
    const float* label = (const float*)d_in[1];
    const float* weight = (const float*)d_in[2];
    const float* bias = (const float*)d_in[3];
    float* out = (float*)d_out;
    float* moved = out;        // 128^3 floats (written by f47 only)
    float* flow = out + V128;  // 3*128^3 floats; pf scratch (interleaved)
    float* fA = (float*)d_ws;  // 3*64^3 floats (g3, interleaved [vox][3])

    conv_kernel<<<dim3(2, 32, 16), 256, 0, stream>>>(features, weight, bias,
                                                     flow);
    f2b_kernel<<<dim3(8, 8, 8), 512, 0, stream>>>(flow, fA);  // steps 1-3
    f47_kernel<<<dim3(8, 8, 8), 512, 0, stream>>>(fA, label, moved, flow);
}

// Round 8
// 294.602 us; speedup vs baseline: 1.0690x; 1.0690x over previous
//
#include <hip/hip_runtime.h>

// Problem: VoxelMorph flow pipeline.
// features [16,128,128,128] f32, moving_label [1,128,128,128] f32,
// weight [3,16,3,3,3] f32, bias [3] f32.
// Output: moved [128^3] then flow [3*128^3], f32, concatenated flat.
//
// R12: flat global-pass integration. Evidence: R6 (adding a dispatch = free)
// + R7 (fusing dispatches = slower) => boundaries are cheap and the ~199us
// phase cost is IN-KERNEL: syncthreads-separated LDS trilerp chains at 2-4
// waves/SIMD + halo recompute, staging a field that is only 3MB (L2-resident
// -- LDS staging of cache-fit data is pure overhead).
// New structure (10 dispatches):
//   conv  : unchanged (93.4us verified)
//   ds    : downsample 128^3 -> 64^3, x1/256, interleaved [vox][3]
//   s1..s7: one thread per voxel: out = f + trisample(f, id + f).
//           8x12B gathers from L2-resident 3MB, no LDS, no sync, no halo.
//   f4up  : per 128^3 voxel: flow = 2*trilerp(g7, g*63/127);
//           moved = trisample(label, g + flow). Planar flow write.

#define V128 2097152      // 128^3
#define V64  262144       // 64^3

typedef __attribute__((ext_vector_type(2))) float f32x2;
typedef float f32x2u __attribute__((ext_vector_type(2), aligned(4)));

// ---------------- trilinear sampler, planar vol (label warp) ---------------
template <int C>
__device__ __forceinline__ void trisample(const float* __restrict__ vol,
                                          int D, int H, int W, int cstride,
                                          float cz, float cy, float cx,
                                          float* out) {
    float fz = floorf(cz), fy = floorf(cy), fx = floorf(cx);
    int iz = (int)fz, iy = (int)fy, ix = (int)fx;
    float tz = cz - fz, ty = cy - fy, tx = cx - fx;
#pragma unroll
    for (int c = 0; c < C; ++c) out[c] = 0.0f;
#pragma unroll
    for (int dz = 0; dz < 2; ++dz) {
#pragma unroll
        for (int dy = 0; dy < 2; ++dy) {
#pragma unroll
            for (int dx = 0; dx < 2; ++dx) {
                int z = iz + dz, y = iy + dy, x = ix + dx;
                float w = (dz ? tz : 1.0f - tz) *
                          (dy ? ty : 1.0f - ty) *
                          (dx ? tx : 1.0f - tx);
                bool valid = (z >= 0) && (z < D) && (y >= 0) && (y < H) &&
                             (x >= 0) && (x < W);
                int zc = min(max(z, 0), D - 1);
                int yc = min(max(y, 0), H - 1);
                int xc = min(max(x, 0), W - 1);
                int base = (zc * H + yc) * W + xc;
                float wv = valid ? w : 0.0f;
#pragma unroll
                for (int c = 0; c < C; ++c)
                    out[c] += vol[c * cstride + base] * wv;
            }
        }
    }
}

// ------- trilinear sampler, interleaved [vox][3] 64^3 volume, masked -------
__device__ __forceinline__ void trisample3i64(const float* __restrict__ vol,
                                              float cz, float cy, float cx,
                                              float* out) {
    float fz = floorf(cz), fy = floorf(cy), fx = floorf(cx);
    int iz = (int)fz, iy = (int)fy, ix = (int)fx;
    float tz = cz - fz, ty = cy - fy, tx = cx - fx;
    out[0] = 0.0f;
    out[1] = 0.0f;
    out[2] = 0.0f;
#pragma unroll
    for (int dz = 0; dz < 2; ++dz) {
#pragma unroll
        for (int dy = 0; dy < 2; ++dy) {
#pragma unroll
            for (int dx = 0; dx < 2; ++dx) {
                int z = iz + dz, y = iy + dy, x = ix + dx;
                float w = (dz ? tz : 1.0f - tz) *
                          (dy ? ty : 1.0f - ty) *
                          (dx ? tx : 1.0f - tx);
                bool valid = ((unsigned)z < 64u) && ((unsigned)y < 64u) &&
                             ((unsigned)x < 64u);
                int zc = min(max(z, 0), 63);
                int yc = min(max(y, 0), 63);
                int xc = min(max(x, 0), 63);
                int b3 = ((zc << 12) + (yc << 6) + xc) * 3;
                float wv = valid ? w : 0.0f;
                out[0] += vol[b3] * wv;
                out[1] += vol[b3 + 1] * wv;
                out[2] += vol[b3 + 2] * wv;
            }
        }
    }
}

// ---------------- K1: conv3d 16->3, 3x3x3, pad 1 (unchanged, 93.4us) -------
__global__ __launch_bounds__(256) void conv_kernel(
    const float* __restrict__ feat, const float* __restrict__ weight,
    const float* __restrict__ bias, float* __restrict__ pf) {
    __shared__ float smem[2][4356];  // 396 columns * 11
    const int tid = threadIdx.x;
    const int x0 = blockIdx.x * 64, y0 = blockIdx.y * 4, z0 = blockIdx.z * 8;
    const int lx = tid & 63, ly = tid >> 6;

    int goff[16];
    int laddr[16];
    unsigned vmask = 0;
#pragma unroll
    for (int k = 0; k < 16; ++k) {
        int s = tid + 256 * k;
        int xx = s % 66;
        int r = s / 66;
        int yy = r % 6;
        int zz = r / 6;
        laddr[k] = (yy * 66 + xx) * 11 + zz;
        bool intile = (k < 15) || (tid < 120);
        int gx = x0 + xx - 1, gy = y0 + yy - 1, gz = z0 + zz - 1;
        bool ok = intile && ((unsigned)gx < 128u) && ((unsigned)gy < 128u) &&
                  ((unsigned)gz < 128u);
        goff[k] = (gz << 14) + (gy << 7) + gx;
        if (ok) vmask |= (1u << k);
    }

    f32x2 acc[3][4];
#pragma unroll
    for (int o = 0; o < 3; ++o)
#pragma unroll
        for (int zp = 0; zp < 4; ++zp) acc[o][zp] = (f32x2)(0.0f);

    {
        float vals[16];
#pragma unroll
        for (int k = 0; k < 16; ++k) {
            vals[k] = 0.0f;
            if (vmask & (1u << k)) vals[k] = feat[goff[k]];
        }
#pragma unroll
        for (int k = 0; k < 16; ++k)
            if (k < 15 || tid < 120) smem[0][laddr[k]] = vals[k];
    }

    for (int c = 0; c < 16; ++c) {
        __syncthreads();
        if (c + 1 < 16) {
            const float* fc = feat + ((c + 1) << 21);
            float* buf = smem[(c + 1) & 1];
            float vals[16];
#pragma unroll
            for (int k = 0; k < 16; ++k) {
                vals[k] = 0.0f;
                if (vmask & (1u << k)) vals[k] = fc[goff[k]];
            }
#pragma unroll
            for (int k = 0; k < 16; ++k)
                if (k < 15 || tid < 120) buf[laddr[k]] = vals[k];
        }
        const float* buf = smem[c & 1];
        const float* wc = weight + c * 27;
#pragma unroll
        for (int dy = 0; dy < 3; ++dy) {
#pragma unroll
            for (int dx = 0; dx < 3; ++dx) {
                const float* p = buf + ((ly + dy) * 66 + lx + dx) * 11;
                f32x2 pv[5];
                f32x2 qv[4];
#pragma unroll
                for (int k2 = 0; k2 < 5; ++k2)
                    pv[k2] = *(const f32x2u*)(p + 2 * k2);
#pragma unroll
                for (int k2 = 0; k2 < 4; ++k2)
                    qv[k2] = *(const f32x2u*)(p + 2 * k2 + 1);
#pragma unroll
                for (int o = 0; o < 3; ++o) {
                    float w0 = wc[o * 432 + 0 + dy * 3 + dx];
                    float w1 = wc[o * 432 + 9 + dy * 3 + dx];
                    float w2 = wc[o * 432 + 18 + dy * 3 + dx];
#pragma unroll
                    for (int zp = 0; zp < 4; ++zp) {
                        acc[o][zp] += pv[zp] * (f32x2)(w0);
                        acc[o][zp] += qv[zp] * (f32x2)(w1);
                        acc[o][zp] += pv[zp + 1] * (f32x2)(w2);
                    }
                }
            }
        }
    }

    float b0 = bias[0], b1 = bias[1], b2 = bias[2];
#pragma unroll
    for (int zp = 0; zp < 4; ++zp) {
        int vox0 = ((z0 + 2 * zp) << 14) + ((y0 + ly) << 7) + x0 + lx;
#pragma unroll
        for (int h = 0; h < 2; ++h) {
            int m3 = (vox0 + (h << 14)) * 3;
            pf[m3] = (h ? acc[0][zp].y : acc[0][zp].x) + b0;
            pf[m3 + 1] = (h ? acc[1][zp].y : acc[1][zp].x) + b1;
            pf[m3 + 2] = (h ? acc[2][zp].y : acc[2][zp].x) + b2;
        }
    }
}

// ------- K2: downsample(127/63) + 1/256 scale, 128^3 -> 64^3 ---------------
// Corner base clamped to <=126/dim (coord exactly 127.0 -> i=126,t=1.0 ==
// reference's zero-weight masked corner, exact).
__global__ __launch_bounds__(256) void ds_kernel(const float* __restrict__ pf,
                                                 float* __restrict__ dsf) {
    int i = blockIdx.x * 256 + threadIdx.x;  // 64^3 samples
    int gx = i & 63, gy = (i >> 6) & 63, gz = i >> 12;
    const float s2 = 127.0f / 63.0f;
    const float k = 1.0f / 256.0f;
    float cz = gz * s2, cy = gy * s2, cx = gx * s2;
    int iz = min((int)cz, 126);
    int iy = min((int)cy, 126);
    int ix = min((int)cx, 126);
    float tzf = cz - (float)iz;
    float tyf = cy - (float)iy;
    float txf = cx - (float)ix;
    float wz[2] = {1.0f - tzf, tzf};
    float wy[2] = {1.0f - tyf, tyf};
    float wx[2] = {1.0f - txf, txf};
    int b = ((iz << 14) + (iy << 7) + ix) * 3;
    float v0 = 0.0f, v1 = 0.0f, v2 = 0.0f;
#pragma unroll
    for (int dz = 0; dz < 2; ++dz)
#pragma unroll
        for (int dy = 0; dy < 2; ++dy)
#pragma unroll
            for (int dx = 0; dx < 2; ++dx) {
                float w = wz[dz] * wy[dy] * wx[dx];
                int bb = b + dz * (3 << 14) + dy * (3 << 7) + dx * 3;
                v0 += pf[bb] * w;
                v1 += pf[bb + 1] * w;
                v2 += pf[bb + 2] * w;
            }
    int o3 = i * 3;
    dsf[o3] = v0 * k;
    dsf[o3 + 1] = v1 * k;
    dsf[o3 + 2] = v2 * k;
}

// ------- K3: one integration step, flat global pass ------------------------
// out[i] = f[i] + trisample(f, id + f[i]); f is 3MB interleaved, L2-resident.
__global__ __launch_bounds__(256) void step_kernel(
    const float* __restrict__ gin, float* __restrict__ gout) {
    int i = blockIdx.x * 256 + threadIdx.x;  // 64^3
    int gx = i & 63, gy = (i >> 6) & 63, gz = i >> 12;
    int i3 = i * 3;
    float fz = gin[i3], fy = gin[i3 + 1], fx = gin[i3 + 2];
    float sm[3];
    trisample3i64(gin, gz + fz, gy + fy, gx + fx, sm);
    gout[i3] = fz + sm[0];
    gout[i3 + 1] = fy + sm[1];
    gout[i3 + 2] = fx + sm[2];
}

// ------- K4: upsample(x2 via 63/127 coords) + label warp -------------------
// flow(g) = 2 * trilerp(g7, g*63/127)   (coords in [0,63], no mask needed;
// base clamped to <=62, t recomputed -> exact at the 63.0 edge).
// moved(g) = trisample(label, g + flow). flow written PLANAR (output layout).
__global__ __launch_bounds__(256) void f4up_kernel(
    const float* __restrict__ g7, const float* __restrict__ label,
    float* __restrict__ moved, float* __restrict__ flow) {
    int m = blockIdx.x * 256 + threadIdx.x;  // 128^3
    int gx = m & 127, gy = (m >> 7) & 127, gz = m >> 14;
    const float s3 = 63.0f / 127.0f;
    float cz = gz * s3, cy = gy * s3, cx = gx * s3;
    int iz = min((int)cz, 62);
    int iy = min((int)cy, 62);
    int ix = min((int)cx, 62);
    float tz = cz - (float)iz, ty = cy - (float)iy, tx = cx - (float)ix;
    float wz[2] = {1.0f - tz, tz};
    float wy[2] = {1.0f - ty, ty};
    float wx[2] = {1.0f - tx, tx};
    int b = ((iz << 12) + (iy << 6) + ix) * 3;
    float f0 = 0.0f, f1 = 0.0f, f2 = 0.0f;
#pragma unroll
    for (int dz = 0; dz < 2; ++dz)
#pragma unroll
        for (int dy = 0; dy < 2; ++dy)
#pragma unroll
            for (int dx = 0; dx < 2; ++dx) {
                float w = wz[dz] * wy[dy] * wx[dx];
                int bb = b + dz * (3 << 12) + dy * (3 << 6) + dx * 3;
                f0 += g7[bb] * w;
                f1 += g7[bb + 1] * w;
                f2 += g7[bb + 2] * w;
            }
    float fz = 2.0f * f0, fy = 2.0f * f1, fx = 2.0f * f2;
    flow[m] = fz;
    flow[m + V128] = fy;
    flow[m + 2 * V128] = fx;
    float mv[1];
    trisample<1>(label, 128, 128, 128, 0, gz + fz, gy + fy, gx + fx, mv);
    moved[m] = mv[0];
}

extern "C" void kernel_launch(void* const* d_in, const int* in_sizes, int n_in,
                              void* d_out, int out_size, void* d_ws,
                              size_t ws_size, hipStream_t stream) {
    const float* features = (const float*)d_in[0];
    const float* label = (const float*)d_in[1];
    const float* weight = (const float*)d_in[2];
    const float* bias = (const float*)d_in[3];
    float* out = (float*)d_out;
    float* moved = out;        // 128^3 floats (written by f4up)
    float* flow = out + V128;  // 3*128^3; pf scratch (interleaved), then final
    float* fA = (float*)d_ws;            // 3*64^3 floats, interleaved
    float* fB = fA + 3 * V64;            // 3*64^3 floats, interleaved

    conv_kernel<<<dim3(2, 32, 16), 256, 0, stream>>>(features, weight, bias,
                                                     flow);
    ds_kernel<<<dim3(1024), 256, 0, stream>>>(flow, fB);      // f0 -> fB
    step_kernel<<<dim3(1024), 256, 0, stream>>>(fB, fA);      // s1
    step_kernel<<<dim3(1024), 256, 0, stream>>>(fA, fB);      // s2
    step_kernel<<<dim3(1024), 256, 0, stream>>>(fB, fA);      // s3
    step_kernel<<<dim3(1024), 256, 0, stream>>>(fA, fB);      // s4
    step_kernel<<<dim3(1024), 256, 0, stream>>>(fB, fA);      // s5
    step_kernel<<<dim3(1024), 256, 0, stream>>>(fA, fB);      // s6
    step_kernel<<<dim3(1024), 256, 0, stream>>>(fB, fA);      // s7
    f4up_kernel<<<dim3(8192), 256, 0, stream>>>(fA, label, moved, flow);
}